// Round 8
// baseline (124.214 us; speedup 1.0000x reference)
//
#include <hip/hip_runtime.h>
#include <math.h>

#define D_INNER 1024
#define STATE   16
#define DT_RANK 64
#define NPROJ   96
#define LSEQ    1024
#define NBATCH  2

// ============ Kernel 1: proj = x @ W_xproj ============
// 256 blocks x 768 threads; 8 rows/block, K split across 8 groups of 128.
__global__ __launch_bounds__(768) void proj_kernel(
        const float* __restrict__ x, const float* __restrict__ Wx,
        float* __restrict__ projdt, float* __restrict__ Bg, float* __restrict__ Cg) {
    const int tid = threadIdx.x;
    const int j  = tid % 96;
    const int kq = tid / 96;              // 0..7
    const int row0 = blockIdx.x * 8;

    const float* wp = Wx + (size_t)(kq * 128) * 96 + j;
    const float* xb = x + (size_t)row0 * 1024 + kq * 128;

    float a[8];
    #pragma unroll
    for (int r = 0; r < 8; ++r) a[r] = 0.f;

    #pragma unroll 4
    for (int k = 0; k < 128; k += 4) {
        float4 xr[8];
        #pragma unroll
        for (int r = 0; r < 8; ++r)
            xr[r] = *(const float4*)(xb + (size_t)r * 1024 + k);
        #pragma unroll
        for (int kk = 0; kk < 4; ++kk) {
            float w = wp[(size_t)(k + kk) * 96];
            #pragma unroll
            for (int r = 0; r < 8; ++r) {
                float xv = (kk == 0) ? xr[r].x : (kk == 1) ? xr[r].y
                         : (kk == 2) ? xr[r].z : xr[r].w;
                a[r] = fmaf(xv, w, a[r]);
            }
        }
    }

    __shared__ float red[8][8][96];       // [kq][r][j] = 24 KB
    #pragma unroll
    for (int r = 0; r < 8; ++r) red[kq][r][j] = a[r];
    __syncthreads();

    {   // 768 outputs, one per thread
        const int r  = tid / 96;
        const int jj = tid % 96;
        float s = 0.f;
        #pragma unroll
        for (int p = 0; p < 8; ++p) s += red[p][r][jj];
        const int row = row0 + r;
        const int b = row >> 10, l = row & 1023;
        if (jj < 64)      projdt[(size_t)row * 64 + jj] = s;
        else if (jj < 80) Bg[((size_t)b * 16 + (jj - 64)) * 1024 + l] = s;
        else              Cg[((size_t)b * 16 + (jj - 80)) * 1024 + l] = s;
    }
}

// ============ Kernel 2: delta (transposed) + u_t = delta * x (transposed) ====
__global__ __launch_bounds__(256) void delta_kernel(
        const float* __restrict__ projdt, const float* __restrict__ Wdt,
        const float* __restrict__ bdt, const float* __restrict__ x,
        float* __restrict__ delta_t, float* __restrict__ u_t) {
    const int bid = blockIdx.x;
    const int lt = bid >> 4;
    const int dt = bid & 15;
    const int row0 = lt * 64;
    const int d0 = dt * 64;
    const int tid = threadIdx.x;

    __shared__ float pl[64][69];
    __shared__ float wlbuf[64 * 68];      // Wdt tile; reused for x tile later
    __shared__ float dtile[64][65];
    float (*wl)[68] = (float(*)[68])wlbuf;

    {
        const float4* src = (const float4*)(projdt + (size_t)row0 * 64);
        #pragma unroll
        for (int i = 0; i < 4; ++i) {
            int f4i = tid + 256 * i;
            float4 v = src[f4i];
            int l = f4i >> 4, k4 = (f4i & 15) << 2;
            pl[l][k4+0] = v.x; pl[l][k4+1] = v.y; pl[l][k4+2] = v.z; pl[l][k4+3] = v.w;
        }
    }
    {
        #pragma unroll
        for (int i = 0; i < 4; ++i) {
            int f4i = tid + 256 * i;
            int k = f4i >> 4, m4 = (f4i & 15) << 2;
            float4 v = *(const float4*)(Wdt + (size_t)k * 1024 + d0 + m4);
            *(float4*)&wl[k][m4] = v;
        }
    }
    __syncthreads();

    const int lsub = tid & 63;
    const int dq = tid >> 6;
    float acc[16];
    #pragma unroll
    for (int i = 0; i < 16; ++i) acc[i] = 0.f;

    #pragma unroll 4
    for (int k = 0; k < 64; ++k) {
        float p = pl[lsub][k];
        const float4* wr = (const float4*)&wl[k][dq * 16];
        float4 w0 = wr[0], w1 = wr[1], w2 = wr[2], w3 = wr[3];
        acc[0]  = fmaf(p, w0.x, acc[0]);  acc[1]  = fmaf(p, w0.y, acc[1]);
        acc[2]  = fmaf(p, w0.z, acc[2]);  acc[3]  = fmaf(p, w0.w, acc[3]);
        acc[4]  = fmaf(p, w1.x, acc[4]);  acc[5]  = fmaf(p, w1.y, acc[5]);
        acc[6]  = fmaf(p, w1.z, acc[6]);  acc[7]  = fmaf(p, w1.w, acc[7]);
        acc[8]  = fmaf(p, w2.x, acc[8]);  acc[9]  = fmaf(p, w2.y, acc[9]);
        acc[10] = fmaf(p, w2.z, acc[10]); acc[11] = fmaf(p, w2.w, acc[11]);
        acc[12] = fmaf(p, w3.x, acc[12]); acc[13] = fmaf(p, w3.y, acc[13]);
        acc[14] = fmaf(p, w3.z, acc[14]); acc[15] = fmaf(p, w3.w, acc[15]);
    }

    #pragma unroll
    for (int i = 0; i < 16; ++i) {
        float v = acc[i] + bdt[d0 + dq * 16 + i];
        float sp = fmaxf(v, 0.f) + log1pf(__expf(-fabsf(v)));
        dtile[dq * 16 + i][lsub] = sp;
    }
    __syncthreads();

    // overlay x tile on dead Wdt storage: xs[l][d]
    float (*xs)[65] = (float(*)[65])wlbuf;   // 64*65*4 <= 64*68*4
    {
        #pragma unroll
        for (int i = 0; i < 4; ++i) {
            int f4i = tid + 256 * i;
            int l = f4i >> 4, m4 = (f4i & 15) << 2;
            float4 v = *(const float4*)(x + (size_t)(row0 + l) * 1024 + d0 + m4);
            xs[l][m4+0] = v.x; xs[l][m4+1] = v.y; xs[l][m4+2] = v.z; xs[l][m4+3] = v.w;
        }
    }
    __syncthreads();

    {
        int dp_ = tid >> 2, seg = tid & 3;
        int b = row0 >> 10, l0 = row0 & 1023;
        size_t off = ((size_t)b * 1024 + d0 + dp_) * 1024 + l0 + seg * 16;
        float* ddst = delta_t + off;
        float* udst = u_t + off;
        #pragma unroll
        for (int m = 0; m < 4; ++m) {
            int lb = seg * 16 + m * 4;
            float4 v;
            v.x = dtile[dp_][lb + 0];
            v.y = dtile[dp_][lb + 1];
            v.z = dtile[dp_][lb + 2];
            v.w = dtile[dp_][lb + 3];
            float4 u;
            u.x = v.x * xs[lb + 0][dp_];
            u.y = v.y * xs[lb + 1][dp_];
            u.z = v.z * xs[lb + 2][dp_];
            u.w = v.w * xs[lb + 3][dp_];
            ((float4*)ddst)[m] = v;
            ((float4*)udst)[m] = u;
        }
    }
}

// ============ Kernel 3: scan, 8-way L split (2 l per lane), n in 2 groups of 8 ====
// Block (512 thr = 8 waves) = ONE (b,d) chain; wave q owns l in [128q,128q+128);
// lane owns 2 consecutive l (one float2). Small live set -> VGPR<=64 naturally.
// Cross-wave stitch via tot[8][8] LDS (broadcast float4 reads); 4 barriers total.
__global__ __launch_bounds__(512) void scan_kernel(
        const float* __restrict__ delta_t, const float* __restrict__ u_t,
        const float* __restrict__ Bg, const float* __restrict__ Cg,
        const float* __restrict__ A_log, float* __restrict__ yout) {
    const int bid0 = blockIdx.x;                       // 0..2047
    const int bid  = (bid0 & 7) * 256 + (bid0 >> 3);   // XCD-chunked swizzle
    const int b = bid >> 10;
    const int d = bid & 1023;
    const int lane = threadIdx.x & 63;
    const int q = threadIdx.x >> 6;                    // wave id 0..7
    const int l0 = q * 128 + lane * 2;

    __shared__ float tot1[8][8];                       // [j][wave]
    __shared__ float tot2[8][8];

    const size_t choff = ((size_t)b * 1024 + d) * 1024 + l0;
    const float2 d2 = *(const float2*)(delta_t + choff);
    const float2 u2 = *(const float2*)(u_t + choff);
    const float* Bp = Bg + (size_t)b * 16 * 1024 + l0;
    const float* Cp = Cg + (size_t)b * 16 * 1024 + l0;

    float y0 = 0.f, y1 = 0.f;

    #pragma unroll 1
    for (int g = 0; g < 2; ++g) {
        float A[8], coff[8], soff[8];
        #pragma unroll
        for (int j = 0; j < 8; ++j)
            A[j] = -__expf(A_log[d * 16 + g * 8 + j]);

        // pass 1: clamped p sums, wave scan
        #pragma unroll
        for (int j = 0; j < 8; ++j) {
            float a = A[j];
            float v = fmaxf(d2.x * a, -7.f) + fmaxf(d2.y * a, -7.f);
            #pragma unroll
            for (int off = 1; off < 64; off <<= 1) {
                float t = __shfl_up(v, off);
                v += (lane >= off) ? t : 0.f;
            }
            if (lane == 63) tot1[j][q] = v;
            float e = __shfl_up(v, 1);
            coff[j] = (lane > 0) ? e : 0.f;
        }
        __syncthreads();
        #pragma unroll
        for (int j = 0; j < 8; ++j) {
            float4 lo = *(const float4*)&tot1[j][0];
            float4 hi = *(const float4*)&tot1[j][4];
            float w = 0.f;
            w += (q > 0) ? lo.x : 0.f;
            w += (q > 1) ? lo.y : 0.f;
            w += (q > 2) ? lo.z : 0.f;
            w += (q > 3) ? lo.w : 0.f;
            w += (q > 4) ? hi.x : 0.f;
            w += (q > 5) ? hi.y : 0.f;
            w += (q > 6) ? hi.z : 0.f;
            coff[j] += w;
        }

        // pass 2: S-term sums, wave scan
        #pragma unroll
        for (int j = 0; j < 8; ++j) {
            float a = A[j];
            float2 bv = *(const float2*)(Bp + (size_t)(g * 8 + j) * 1024);
            float c = coff[j], v;
            c += fmaxf(d2.x * a, -7.f);
            v  = u2.x * bv.x * __expf(fminf(-c, 20.f));
            c += fmaxf(d2.y * a, -7.f);
            v  = fmaf(u2.y * bv.y, __expf(fminf(-c, 20.f)), v);
            #pragma unroll
            for (int off = 1; off < 64; off <<= 1) {
                float t = __shfl_up(v, off);
                v += (lane >= off) ? t : 0.f;
            }
            if (lane == 63) tot2[j][q] = v;
            float e = __shfl_up(v, 1);
            soff[j] = (lane > 0) ? e : 0.f;
        }
        __syncthreads();
        #pragma unroll
        for (int j = 0; j < 8; ++j) {
            float4 lo = *(const float4*)&tot2[j][0];
            float4 hi = *(const float4*)&tot2[j][4];
            float w = 0.f;
            w += (q > 0) ? lo.x : 0.f;
            w += (q > 1) ? lo.y : 0.f;
            w += (q > 2) ? lo.z : 0.f;
            w += (q > 3) ? lo.w : 0.f;
            w += (q > 4) ? hi.x : 0.f;
            w += (q > 5) ? hi.y : 0.f;
            w += (q > 6) ? hi.z : 0.f;
            soff[j] += w;
        }

        // pass 3: final walk, y accumulate
        #pragma unroll
        for (int j = 0; j < 8; ++j) {
            float a = A[j];
            float2 bv = *(const float2*)(Bp + (size_t)(g * 8 + j) * 1024);
            float2 cv = *(const float2*)(Cp + (size_t)(g * 8 + j) * 1024);
            float c = coff[j], s = soff[j];

            c += fmaxf(d2.x * a, -7.f);
            s  = fmaf(u2.x * bv.x, __expf(fminf(-c, 20.f)), s);
            y0 = fmaf(cv.x * __expf(c), s, y0);

            c += fmaxf(d2.y * a, -7.f);
            s  = fmaf(u2.y * bv.y, __expf(fminf(-c, 20.f)), s);
            y1 = fmaf(cv.y * __expf(c), s, y1);
        }
    }

    *(float2*)(yout + choff) = make_float2(y0, y1);
}

// ============ Kernel 4: in-place tile-pair transpose of yout + x*D fixup ====
// yout currently holds M[b][d][l]; final y[b][l][d] = M[b][d'][l'] transposed
// + x*D. Block owns tiles (ti,tj) and (tj,ti) -> no cross-block hazard.
__global__ __launch_bounds__(256) void finish_kernel(
        const float* __restrict__ x, const float* __restrict__ Dvec,
        float* __restrict__ yout) {
    const int bid = blockIdx.x;            // 0..271
    const int b = bid / 136;
    int p = bid % 136;
    int ti = 0;
    while (p >= (16 - ti)) { p -= (16 - ti); ++ti; }
    const int tj = ti + p;
    const int tid = threadIdx.x;

    __shared__ float LA[64][65];           // M(tj, ti)
    __shared__ float LB[64][65];           // M(ti, tj)

    float* Mb = yout + (size_t)b * 1024 * 1024;
    const float* xb = x + (size_t)b * 1024 * 1024;

    #pragma unroll
    for (int i = 0; i < 4; ++i) {
        int fi = tid + 256 * i;
        int r = fi >> 4, c4 = (fi & 15) << 2;
        float4 v = *(const float4*)(Mb + (size_t)(tj * 64 + r) * 1024 + ti * 64 + c4);
        LA[r][c4+0] = v.x; LA[r][c4+1] = v.y; LA[r][c4+2] = v.z; LA[r][c4+3] = v.w;
    }
    if (ti != tj) {
        #pragma unroll
        for (int i = 0; i < 4; ++i) {
            int fi = tid + 256 * i;
            int r = fi >> 4, c4 = (fi & 15) << 2;
            float4 v = *(const float4*)(Mb + (size_t)(ti * 64 + r) * 1024 + tj * 64 + c4);
            LB[r][c4+0] = v.x; LB[r][c4+1] = v.y; LB[r][c4+2] = v.z; LB[r][c4+3] = v.w;
        }
    }
    __syncthreads();

    // final(ti,tj)[r][c] = LA[c][r] + x[ti*64+r][tj*64+c] * D[tj*64+c]
    #pragma unroll
    for (int i = 0; i < 4; ++i) {
        int fi = tid + 256 * i;
        int r = fi >> 4, c4 = (fi & 15) << 2;
        size_t off = (size_t)(ti * 64 + r) * 1024 + tj * 64 + c4;
        float4 xv = *(const float4*)(xb + off);
        float4 dv = *(const float4*)(Dvec + tj * 64 + c4);
        float4 o;
        o.x = fmaf(xv.x, dv.x, LA[c4+0][r]);
        o.y = fmaf(xv.y, dv.y, LA[c4+1][r]);
        o.z = fmaf(xv.z, dv.z, LA[c4+2][r]);
        o.w = fmaf(xv.w, dv.w, LA[c4+3][r]);
        *(float4*)(Mb + off) = o;
    }
    if (ti != tj) {
        #pragma unroll
        for (int i = 0; i < 4; ++i) {
            int fi = tid + 256 * i;
            int r = fi >> 4, c4 = (fi & 15) << 2;
            size_t off = (size_t)(tj * 64 + r) * 1024 + ti * 64 + c4;
            float4 xv = *(const float4*)(xb + off);
            float4 dv = *(const float4*)(Dvec + ti * 64 + c4);
            float4 o;
            o.x = fmaf(xv.x, dv.x, LB[c4+0][r]);
            o.y = fmaf(xv.y, dv.y, LB[c4+1][r]);
            o.z = fmaf(xv.z, dv.z, LB[c4+2][r]);
            o.w = fmaf(xv.w, dv.w, LB[c4+3][r]);
            *(float4*)(Mb + off) = o;
        }
    }
}

extern "C" void kernel_launch(void* const* d_in, const int* in_sizes, int n_in,
                              void* d_out, int out_size, void* d_ws, size_t ws_size,
                              hipStream_t stream) {
    const float* x    = (const float*)d_in[0];
    const float* Wx   = (const float*)d_in[1];
    const float* Wdt  = (const float*)d_in[2];
    const float* bdt  = (const float*)d_in[3];
    const float* Alog = (const float*)d_in[4];
    const float* Dvec = (const float*)d_in[5];
    float* y = (float*)d_out;

    // ws (floats): projdt 131072 | Bg 32768 | Cg 32768 | delta_t 2M | u_t 2M  (~16.8 MB)
    float* projdt  = (float*)d_ws;
    float* Bgp     = projdt + (size_t)2048 * 64;
    float* Cgp     = Bgp + (size_t)2 * 16 * 1024;
    float* delta_t = Cgp + (size_t)2 * 16 * 1024;
    float* u_t     = delta_t + (size_t)2 * 1024 * 1024;

    proj_kernel<<<256, 768, 0, stream>>>(x, Wx, projdt, Bgp, Cgp);
    delta_kernel<<<512, 256, 0, stream>>>(projdt, Wdt, bdt, x, delta_t, u_t);
    scan_kernel<<<2048, 512, 0, stream>>>(delta_t, u_t, Bgp, Cgp, Alog, y);
    finish_kernel<<<272, 256, 0, stream>>>(x, Dvec, y);
}

// Round 9
// 85.723 us; speedup vs baseline: 1.4490x; 1.4490x over previous
//
#include <hip/hip_runtime.h>
#include <math.h>

#define D_INNER 1024
#define STATE   16
#define DT_RANK 64
#define NPROJ   96
#define LSEQ    1024
#define NBATCH  2

#define LOG2E   1.4426950408889634f
#define NEG7L2  (-7.0f * LOG2E)     // clamp lo in log2 domain
#define P20L2   (20.0f * LOG2E)     // clamp hi in log2 domain

// ---- 64-lane inclusive scan via DPP (GCN idiom), 6 adds ----
template<int CTRL, int RMASK>
__device__ __forceinline__ float dppadd(float v) {
    int t = __builtin_amdgcn_update_dpp(0, __float_as_int(v), CTRL, RMASK, 0xf, false);
    return v + __int_as_float(t);
}
__device__ __forceinline__ float wave_iscan(float v) {
    v = dppadd<0x111, 0xf>(v);   // row_shr:1
    v = dppadd<0x112, 0xf>(v);   // row_shr:2
    v = dppadd<0x114, 0xf>(v);   // row_shr:4
    v = dppadd<0x118, 0xf>(v);   // row_shr:8
    v = dppadd<0x142, 0xa>(v);   // row_bcast:15 -> rows 1,3
    v = dppadd<0x143, 0xc>(v);   // row_bcast:31 -> rows 2,3
    return v;
}

// ============ Kernel 1: proj = x @ W_xproj ============
__global__ __launch_bounds__(768) void proj_kernel(
        const float* __restrict__ x, const float* __restrict__ Wx,
        float* __restrict__ projdt, float* __restrict__ Bg, float* __restrict__ Cg) {
    const int tid = threadIdx.x;
    const int j  = tid % 96;
    const int kq = tid / 96;              // 0..7
    const int row0 = blockIdx.x * 8;

    const float* wp = Wx + (size_t)(kq * 128) * 96 + j;
    const float* xb = x + (size_t)row0 * 1024 + kq * 128;

    float a[8];
    #pragma unroll
    for (int r = 0; r < 8; ++r) a[r] = 0.f;

    #pragma unroll 4
    for (int k = 0; k < 128; k += 4) {
        float4 xr[8];
        #pragma unroll
        for (int r = 0; r < 8; ++r)
            xr[r] = *(const float4*)(xb + (size_t)r * 1024 + k);
        #pragma unroll
        for (int kk = 0; kk < 4; ++kk) {
            float w = wp[(size_t)(k + kk) * 96];
            #pragma unroll
            for (int r = 0; r < 8; ++r) {
                float xv = (kk == 0) ? xr[r].x : (kk == 1) ? xr[r].y
                         : (kk == 2) ? xr[r].z : xr[r].w;
                a[r] = fmaf(xv, w, a[r]);
            }
        }
    }

    __shared__ float red[8][8][96];       // [kq][r][j] = 24 KB
    #pragma unroll
    for (int r = 0; r < 8; ++r) red[kq][r][j] = a[r];
    __syncthreads();

    {   // 768 outputs, one per thread
        const int r  = tid / 96;
        const int jj = tid % 96;
        float s = 0.f;
        #pragma unroll
        for (int p = 0; p < 8; ++p) s += red[p][r][jj];
        const int row = row0 + r;
        const int b = row >> 10, l = row & 1023;
        if (jj < 64)      projdt[(size_t)row * 64 + jj] = s;
        else if (jj < 80) Bg[((size_t)b * 16 + (jj - 64)) * 1024 + l] = s;
        else              Cg[((size_t)b * 16 + (jj - 80)) * 1024 + l] = s;
    }
}

// ============ Kernel 2: delta (transposed) + u_t = delta * x (transposed) ====
__global__ __launch_bounds__(256) void delta_kernel(
        const float* __restrict__ projdt, const float* __restrict__ Wdt,
        const float* __restrict__ bdt, const float* __restrict__ x,
        float* __restrict__ delta_t, float* __restrict__ u_t) {
    const int bid = blockIdx.x;
    const int lt = bid >> 4;
    const int dt = bid & 15;
    const int row0 = lt * 64;
    const int d0 = dt * 64;
    const int tid = threadIdx.x;

    __shared__ float pl[64][69];
    __shared__ float wlbuf[64 * 68];      // Wdt tile; reused for x tile later
    __shared__ float dtile[64][65];
    float (*wl)[68] = (float(*)[68])wlbuf;

    {
        const float4* src = (const float4*)(projdt + (size_t)row0 * 64);
        #pragma unroll
        for (int i = 0; i < 4; ++i) {
            int f4i = tid + 256 * i;
            float4 v = src[f4i];
            int l = f4i >> 4, k4 = (f4i & 15) << 2;
            pl[l][k4+0] = v.x; pl[l][k4+1] = v.y; pl[l][k4+2] = v.z; pl[l][k4+3] = v.w;
        }
    }
    {
        #pragma unroll
        for (int i = 0; i < 4; ++i) {
            int f4i = tid + 256 * i;
            int k = f4i >> 4, m4 = (f4i & 15) << 2;
            float4 v = *(const float4*)(Wdt + (size_t)k * 1024 + d0 + m4);
            *(float4*)&wl[k][m4] = v;
        }
    }
    __syncthreads();

    const int lsub = tid & 63;
    const int dq = tid >> 6;
    float acc[16];
    #pragma unroll
    for (int i = 0; i < 16; ++i) acc[i] = 0.f;

    #pragma unroll 4
    for (int k = 0; k < 64; ++k) {
        float p = pl[lsub][k];
        const float4* wr = (const float4*)&wl[k][dq * 16];
        float4 w0 = wr[0], w1 = wr[1], w2 = wr[2], w3 = wr[3];
        acc[0]  = fmaf(p, w0.x, acc[0]);  acc[1]  = fmaf(p, w0.y, acc[1]);
        acc[2]  = fmaf(p, w0.z, acc[2]);  acc[3]  = fmaf(p, w0.w, acc[3]);
        acc[4]  = fmaf(p, w1.x, acc[4]);  acc[5]  = fmaf(p, w1.y, acc[5]);
        acc[6]  = fmaf(p, w1.z, acc[6]);  acc[7]  = fmaf(p, w1.w, acc[7]);
        acc[8]  = fmaf(p, w2.x, acc[8]);  acc[9]  = fmaf(p, w2.y, acc[9]);
        acc[10] = fmaf(p, w2.z, acc[10]); acc[11] = fmaf(p, w2.w, acc[11]);
        acc[12] = fmaf(p, w3.x, acc[12]); acc[13] = fmaf(p, w3.y, acc[13]);
        acc[14] = fmaf(p, w3.z, acc[14]); acc[15] = fmaf(p, w3.w, acc[15]);
    }

    #pragma unroll
    for (int i = 0; i < 16; ++i) {
        float v = acc[i] + bdt[d0 + dq * 16 + i];
        float sp = fmaxf(v, 0.f) + log1pf(__expf(-fabsf(v)));
        dtile[dq * 16 + i][lsub] = sp;
    }
    __syncthreads();

    // overlay x tile on dead Wdt storage: xs[l][d]
    float (*xs)[65] = (float(*)[65])wlbuf;   // 64*65*4 <= 64*68*4
    {
        #pragma unroll
        for (int i = 0; i < 4; ++i) {
            int f4i = tid + 256 * i;
            int l = f4i >> 4, m4 = (f4i & 15) << 2;
            float4 v = *(const float4*)(x + (size_t)(row0 + l) * 1024 + d0 + m4);
            xs[l][m4+0] = v.x; xs[l][m4+1] = v.y; xs[l][m4+2] = v.z; xs[l][m4+3] = v.w;
        }
    }
    __syncthreads();

    {
        int dp_ = tid >> 2, seg = tid & 3;
        int b = row0 >> 10, l0 = row0 & 1023;
        size_t off = ((size_t)b * 1024 + d0 + dp_) * 1024 + l0 + seg * 16;
        float* ddst = delta_t + off;
        float* udst = u_t + off;
        #pragma unroll
        for (int m = 0; m < 4; ++m) {
            int lb = seg * 16 + m * 4;
            float4 v;
            v.x = dtile[dp_][lb + 0];
            v.y = dtile[dp_][lb + 1];
            v.z = dtile[dp_][lb + 2];
            v.w = dtile[dp_][lb + 3];
            float4 u;
            u.x = v.x * xs[lb + 0][dp_];
            u.y = v.y * xs[lb + 1][dp_];
            u.z = v.z * xs[lb + 2][dp_];
            u.w = v.w * xs[lb + 3][dp_];
            ((float4*)ddst)[m] = v;
            ((float4*)udst)[m] = u;
        }
    }
}

// ============ Kernel 3: scan, 4-way L split, groups of 4 states ============
// r6 geometry (block = 4 waves = one (b,d) chain, lane owns 4 consecutive l),
// with DPP prefix scans (6 v_add_dpp vs 18-instr shfl butterfly), log2-domain
// cumsum (exp2f, no per-exp mul), exclusive prefix = inclusive - own.
__global__ __launch_bounds__(256) void scan_kernel(
        const float* __restrict__ delta_t, const float* __restrict__ u_t,
        const float* __restrict__ Bg, const float* __restrict__ Cg,
        const float* __restrict__ A_log, float* __restrict__ yout) {
    const int bid0 = blockIdx.x;                       // 0..2047
    const int bid  = (bid0 & 7) * 256 + (bid0 >> 3);   // XCD-chunked swizzle
    const int b = bid >> 10;
    const int d = bid & 1023;
    const int lane = threadIdx.x & 63;
    const int q = threadIdx.x >> 6;                    // L-quarter 0..3
    const int l0 = q * 256 + lane * 4;

    __shared__ float tot1[4][4];
    __shared__ float tot2[4][4];

    const size_t choff = ((size_t)b * 1024 + d) * 1024 + l0;
    const float4 d4 = *(const float4*)(delta_t + choff);
    const float4 u4 = *(const float4*)(u_t + choff);
    const float* Bp = Bg + (size_t)b * 16 * 1024 + l0;
    const float* Cp = Cg + (size_t)b * 16 * 1024 + l0;

    float y0 = 0.f, y1 = 0.f, y2 = 0.f, y3 = 0.f;

    #pragma unroll 1
    for (int g = 0; g < 4; ++g) {
        float A2[4], coff[4], soff[4];
        #pragma unroll
        for (int j = 0; j < 4; ++j)
            A2[j] = -__expf(A_log[d * 16 + g * 4 + j]) * LOG2E;

        // pass 1: clamped p sums (log2 domain), DPP scan
        #pragma unroll
        for (int j = 0; j < 4; ++j) {
            float a = A2[j];
            float local = fmaxf(d4.x * a, NEG7L2) + fmaxf(d4.y * a, NEG7L2)
                        + fmaxf(d4.z * a, NEG7L2) + fmaxf(d4.w * a, NEG7L2);
            float incl = wave_iscan(local);
            if (lane == 63) tot1[j][q] = incl;
            coff[j] = incl - local;
        }
        __syncthreads();
        #pragma unroll
        for (int j = 0; j < 4; ++j) {
            float4 t = *(const float4*)&tot1[j][0];
            float w = 0.f;
            w += (q > 0) ? t.x : 0.f;
            w += (q > 1) ? t.y : 0.f;
            w += (q > 2) ? t.z : 0.f;
            coff[j] += w;
        }

        // pass 2: S-term sums, DPP scan
        #pragma unroll
        for (int j = 0; j < 4; ++j) {
            float a = A2[j];
            float4 bv = *(const float4*)(Bp + (size_t)(g * 4 + j) * 1024);
            float c = coff[j], local;
            c += fmaxf(d4.x * a, NEG7L2);
            local = u4.x * bv.x * exp2f(fminf(-c, P20L2));
            c += fmaxf(d4.y * a, NEG7L2);
            local = fmaf(u4.y * bv.y, exp2f(fminf(-c, P20L2)), local);
            c += fmaxf(d4.z * a, NEG7L2);
            local = fmaf(u4.z * bv.z, exp2f(fminf(-c, P20L2)), local);
            c += fmaxf(d4.w * a, NEG7L2);
            local = fmaf(u4.w * bv.w, exp2f(fminf(-c, P20L2)), local);
            float incl = wave_iscan(local);
            if (lane == 63) tot2[j][q] = incl;
            soff[j] = incl - local;
        }
        __syncthreads();
        #pragma unroll
        for (int j = 0; j < 4; ++j) {
            float4 t = *(const float4*)&tot2[j][0];
            float w = 0.f;
            w += (q > 0) ? t.x : 0.f;
            w += (q > 1) ? t.y : 0.f;
            w += (q > 2) ? t.z : 0.f;
            soff[j] += w;
        }

        // pass 3: final walk, y accumulate
        #pragma unroll
        for (int j = 0; j < 4; ++j) {
            float a = A2[j];
            float4 bv = *(const float4*)(Bp + (size_t)(g * 4 + j) * 1024);
            float4 cv = *(const float4*)(Cp + (size_t)(g * 4 + j) * 1024);
            float c = coff[j], s = soff[j];

            c += fmaxf(d4.x * a, NEG7L2);
            s  = fmaf(u4.x * bv.x, exp2f(fminf(-c, P20L2)), s);
            y0 = fmaf(cv.x * exp2f(c), s, y0);

            c += fmaxf(d4.y * a, NEG7L2);
            s  = fmaf(u4.y * bv.y, exp2f(fminf(-c, P20L2)), s);
            y1 = fmaf(cv.y * exp2f(c), s, y1);

            c += fmaxf(d4.z * a, NEG7L2);
            s  = fmaf(u4.z * bv.z, exp2f(fminf(-c, P20L2)), s);
            y2 = fmaf(cv.z * exp2f(c), s, y2);

            c += fmaxf(d4.w * a, NEG7L2);
            s  = fmaf(u4.w * bv.w, exp2f(fminf(-c, P20L2)), s);
            y3 = fmaf(cv.w * exp2f(c), s, y3);
        }
    }

    *(float4*)(yout + choff) = make_float4(y0, y1, y2, y3);
}

// ============ Kernel 4: in-place tile-pair transpose of yout + x*D fixup ====
__global__ __launch_bounds__(256) void finish_kernel(
        const float* __restrict__ x, const float* __restrict__ Dvec,
        float* __restrict__ yout) {
    const int bid = blockIdx.x;            // 0..271
    const int b = bid / 136;
    int p = bid % 136;
    int ti = 0;
    while (p >= (16 - ti)) { p -= (16 - ti); ++ti; }
    const int tj = ti + p;
    const int tid = threadIdx.x;

    __shared__ float LA[64][65];           // M(tj, ti)
    __shared__ float LB[64][65];           // M(ti, tj)

    float* Mb = yout + (size_t)b * 1024 * 1024;
    const float* xb = x + (size_t)b * 1024 * 1024;

    #pragma unroll
    for (int i = 0; i < 4; ++i) {
        int fi = tid + 256 * i;
        int r = fi >> 4, c4 = (fi & 15) << 2;
        float4 v = *(const float4*)(Mb + (size_t)(tj * 64 + r) * 1024 + ti * 64 + c4);
        LA[r][c4+0] = v.x; LA[r][c4+1] = v.y; LA[r][c4+2] = v.z; LA[r][c4+3] = v.w;
    }
    if (ti != tj) {
        #pragma unroll
        for (int i = 0; i < 4; ++i) {
            int fi = tid + 256 * i;
            int r = fi >> 4, c4 = (fi & 15) << 2;
            float4 v = *(const float4*)(Mb + (size_t)(ti * 64 + r) * 1024 + tj * 64 + c4);
            LB[r][c4+0] = v.x; LB[r][c4+1] = v.y; LB[r][c4+2] = v.z; LB[r][c4+3] = v.w;
        }
    }
    __syncthreads();

    #pragma unroll
    for (int i = 0; i < 4; ++i) {
        int fi = tid + 256 * i;
        int r = fi >> 4, c4 = (fi & 15) << 2;
        size_t off = (size_t)(ti * 64 + r) * 1024 + tj * 64 + c4;
        float4 xv = *(const float4*)(xb + off);
        float4 dv = *(const float4*)(Dvec + tj * 64 + c4);
        float4 o;
        o.x = fmaf(xv.x, dv.x, LA[c4+0][r]);
        o.y = fmaf(xv.y, dv.y, LA[c4+1][r]);
        o.z = fmaf(xv.z, dv.z, LA[c4+2][r]);
        o.w = fmaf(xv.w, dv.w, LA[c4+3][r]);
        *(float4*)(Mb + off) = o;
    }
    if (ti != tj) {
        #pragma unroll
        for (int i = 0; i < 4; ++i) {
            int fi = tid + 256 * i;
            int r = fi >> 4, c4 = (fi & 15) << 2;
            size_t off = (size_t)(tj * 64 + r) * 1024 + ti * 64 + c4;
            float4 xv = *(const float4*)(xb + off);
            float4 dv = *(const float4*)(Dvec + ti * 64 + c4);
            float4 o;
            o.x = fmaf(xv.x, dv.x, LB[c4+0][r]);
            o.y = fmaf(xv.y, dv.y, LB[c4+1][r]);
            o.z = fmaf(xv.z, dv.z, LB[c4+2][r]);
            o.w = fmaf(xv.w, dv.w, LB[c4+3][r]);
            *(float4*)(Mb + off) = o;
        }
    }
}

extern "C" void kernel_launch(void* const* d_in, const int* in_sizes, int n_in,
                              void* d_out, int out_size, void* d_ws, size_t ws_size,
                              hipStream_t stream) {
    const float* x    = (const float*)d_in[0];
    const float* Wx   = (const float*)d_in[1];
    const float* Wdt  = (const float*)d_in[2];
    const float* bdt  = (const float*)d_in[3];
    const float* Alog = (const float*)d_in[4];
    const float* Dvec = (const float*)d_in[5];
    float* y = (float*)d_out;

    // ws (floats): projdt 131072 | Bg 32768 | Cg 32768 | delta_t 2M | u_t 2M  (~16.8 MB)
    float* projdt  = (float*)d_ws;
    float* Bgp     = projdt + (size_t)2048 * 64;
    float* Cgp     = Bgp + (size_t)2 * 16 * 1024;
    float* delta_t = Cgp + (size_t)2 * 16 * 1024;
    float* u_t     = delta_t + (size_t)2 * 1024 * 1024;

    proj_kernel<<<256, 768, 0, stream>>>(x, Wx, projdt, Bgp, Cgp);
    delta_kernel<<<512, 256, 0, stream>>>(projdt, Wdt, bdt, x, delta_t, u_t);
    scan_kernel<<<2048, 256, 0, stream>>>(delta_t, u_t, Bgp, Cgp, Alog, y);
    finish_kernel<<<272, 256, 0, stream>>>(x, Dvec, y);
}